// Round 5
// baseline (416.167 us; speedup 1.0000x reference)
//
#include <hip/hip_runtime.h>

typedef unsigned short u16;
typedef __bf16 bf8_t __attribute__((ext_vector_type(8)));
typedef short short8 __attribute__((ext_vector_type(8)));
typedef u16 u16x4 __attribute__((ext_vector_type(4)));
typedef float f32x4 __attribute__((ext_vector_type(4)));

#define DEV __device__ __forceinline__

DEV u16 f2bf(float x) {
  unsigned u = __builtin_bit_cast(unsigned, x);
  return (u16)((u + 0x7FFFu + ((u >> 16) & 1u)) >> 16);
}
DEV float bf2f(u16 x) {
  unsigned u = (unsigned)x << 16;
  return __builtin_bit_cast(float, u);
}

DEV void gload16(const u16* g, u16* l) {
  __builtin_amdgcn_global_load_lds((__attribute__((address_space(1))) void*)(g),
                                   (__attribute__((address_space(3))) void*)(l), 16, 0, 0);
}

// ---------------- K0a: pointwise weights fp32 -> bf16, stacked [3*512][512], float4 ----------------
__global__ void k_wconv(const float* __restrict__ f, const float* __restrict__ g,
                        const float* __restrict__ h, u16* __restrict__ out) {
  int i4 = (blockIdx.x * 256 + threadIdx.x) * 4;   // 0..786428, 262144-aligned chunks
  const float* src = (i4 < 262144) ? (f + i4) : (i4 < 524288) ? (g + i4 - 262144) : (h + i4 - 524288);
  f32x4 v = *(const f32x4*)src;
  u16x4 o;
#pragma unroll
  for (int e = 0; e < 4; ++e) o[e] = f2bf(v[e]);
  *(u16x4*)(out + i4) = o;
}

// ---------------- K0b: style [b][c][n] fp32 -> Xt [b][n][c] bf16 ----------------
__global__ __launch_bounds__(256) void k_xt(const float* __restrict__ style, u16* __restrict__ Xt) {
  __shared__ float t[32][33];
  int b = blockIdx.z, c0 = blockIdx.y * 32, n0 = blockIdx.x * 32;
  int tid = threadIdx.x, lr = tid >> 5, lc = tid & 31;
  const float* src = style + ((size_t)b * 512 + c0) * 4096 + n0;
#pragma unroll
  for (int it = 0; it < 4; ++it) {
    int r = it * 8 + lr;
    t[r][lc] = src[(size_t)r * 4096 + lc];
  }
  __syncthreads();
  // vectorized store: thread -> 4 consecutive c for one n
  int cs = (tid & 7) * 4, n = tid >> 3;
  u16x4 s;
#pragma unroll
  for (int j = 0; j < 4; ++j) s[j] = f2bf(t[cs + j][n]);
  *(u16x4*)(Xt + ((size_t)b * 4096 + n0 + n) * 512 + c0 + cs) = s;
}

// ---------------- 128x128 GEMM staging helper (validated round-1 structure) ----------------
DEV void stage_tile(const u16* __restrict__ src, int row0, int kb,
                    u16* lds, int wave, int lane) {
#pragma unroll
  for (int qq = 0; qq < 2; ++qq) {
    int idx = (wave * 2 + qq) * 64 + lane;   // 0..511 16B-chunk id
    int r = idx >> 2;
    int cb = (idx & 3) * 8;
    gload16(src + (size_t)(row0 + r) * 512 + (kb + cb),
            lds + (wave * 2 + qq) * 512);    // wave-uniform base; HW adds lane*16B
  }
}

// ---------------- K1: Y[b][1536][4096] = Wall[1536][512] @ Xt[b][4096][512]^T ----------------
// EXACT round-1 dispatch order (x=32 N-tiles, y=4 M-tiles, z=t*16+b), measured 144.6us.
__global__ __launch_bounds__(256, 2) void k_gemm_branch(
    const u16* __restrict__ Wall, const u16* __restrict__ Xt, u16* __restrict__ Y) {
  int z = blockIdx.z;
  int t = z >> 4, b = z & 15;
  int M0 = t * 512 + blockIdx.y * 128, N0 = blockIdx.x * 128;
  const u16* A = Wall;                                  // [1536][512]
  const u16* B = Xt + (size_t)b * (4096 * 512);         // [4096][512]
  u16* C = Y + (size_t)b * (1536 * 4096);
  int tid = threadIdx.x, wave = tid >> 6, lane = tid & 63;
  int wm = wave >> 1, wn = wave & 1;
  __shared__ __align__(16) u16 lA[2][128 * 32];
  __shared__ __align__(16) u16 lB[2][128 * 32];
  f32x4 acc[4][4];
#pragma unroll
  for (int m = 0; m < 4; ++m)
#pragma unroll
    for (int n = 0; n < 4; ++n) acc[m][n] = (f32x4){0.f, 0.f, 0.f, 0.f};
  stage_tile(A, M0, 0, &lA[0][0], wave, lane);
  stage_tile(B, N0, 0, &lB[0][0], wave, lane);
  __syncthreads();
  int lrow = lane & 15, lk = (lane >> 4) * 8;
#pragma unroll 2
  for (int kt = 0; kt < 16; ++kt) {
    int cur = kt & 1;
    if (kt < 15) {
      stage_tile(A, M0, (kt + 1) * 32, &lA[cur ^ 1][0], wave, lane);
      stage_tile(B, N0, (kt + 1) * 32, &lB[cur ^ 1][0], wave, lane);
    }
    bf8_t af[4], bff[4];
#pragma unroll
    for (int m = 0; m < 4; ++m)
      af[m] = *(const bf8_t*)&lA[cur][(wm * 64 + m * 16 + lrow) * 32 + lk];
#pragma unroll
    for (int n = 0; n < 4; ++n)
      bff[n] = *(const bf8_t*)&lB[cur][(wn * 64 + n * 16 + lrow) * 32 + lk];
#pragma unroll
    for (int m = 0; m < 4; ++m)
#pragma unroll
      for (int n = 0; n < 4; ++n)
        acc[m][n] = __builtin_amdgcn_mfma_f32_16x16x32_bf16(af[m], bff[n], acc[m][n], 0, 0, 0);
    __syncthreads();
  }
  int orow = (lane >> 4) * 4, ocol = lane & 15;
#pragma unroll
  for (int m = 0; m < 4; ++m)
#pragma unroll
    for (int n = 0; n < 4; ++n) {
      int row = M0 + wm * 64 + m * 16 + orow;
      int col = N0 + wn * 64 + n * 16 + ocol;
      u16* cp = C + (size_t)row * 4096 + col;
#pragma unroll
      for (int i = 0; i < 4; ++i) cp[(size_t)i * 4096] = f2bf(acc[m][n][i]);
    }
}

// ---------------- fused depthwise row computation ----------------
template <typename F>
DEV void dw_row(const u16* plane, const float* w9, int y, F&& store) {
  short8 raw[3][8];
#pragma unroll
  for (int i = 0; i < 3; ++i) {
    int yy = y + 2 * i - 2;
    yy = yy < 0 ? -yy : (yy > 63 ? 126 - yy : yy);
    const short8* rp = (const short8*)(plane + yy * 64);
#pragma unroll
    for (int ch = 0; ch < 8; ++ch) raw[i][ch] = rp[ch];
  }
#pragma unroll
  for (int g = 0; g < 4; ++g) {
    float fr[3][20];
#pragma unroll
    for (int t = 0; t < 20; ++t) {
      int p = g * 16 - 2 + t;
      int rp2 = p < 0 ? -p : (p > 63 ? 126 - p : p);
#pragma unroll
      for (int i = 0; i < 3; ++i)
        fr[i][t] = bf2f((u16)raw[i][rp2 >> 3][rp2 & 7]);
    }
    float o[16];
#pragma unroll
    for (int e = 0; e < 16; ++e) {
      float s = 0.f;
#pragma unroll
      for (int i = 0; i < 3; ++i)
#pragma unroll
        for (int j = 0; j < 3; ++j)
          s += w9[i * 3 + j] * fr[i][e + 2 * j];
      o[e] = s;
    }
    store(g, o);
  }
}

// ---------------- K2: fused dw(q),dw(k) -> partial Gram E[band][b][h][64][64] ----------------
__global__ __launch_bounds__(256, 2) void k_dwE(const u16* __restrict__ Y,
    const float* __restrict__ fwd, const float* __restrict__ gwd, float* __restrict__ E) {
  int band = blockIdx.x, h = blockIdx.y, b = blockIdx.z;
  __shared__ __align__(16) u16 qbuf[64 * 256];
  __shared__ __align__(16) u16 kbuf[64 * 256];
  int tid = threadIdx.x;
  int c = ((tid >> 5) << 3) | (tid & 7);
  int yl = (tid >> 3) & 3;
  int wv = tid >> 6, lane = tid & 63;
  int lrow = lane & 15, lkg = lane >> 4;
  const u16* qp = Y + ((size_t)b * 1536 + h * 64 + c) * 4096;
  const u16* kp = Y + ((size_t)b * 1536 + 512 + h * 64 + c) * 4096;
  float wq9[9], wk9[9];
#pragma unroll
  for (int t = 0; t < 9; ++t) {
    wq9[t] = fwd[(h * 64 + c) * 9 + t];
    wk9[t] = gwd[(h * 64 + c) * 9 + t];
  }
  f32x4 acc[4];
#pragma unroll
  for (int n = 0; n < 4; ++n) acc[n] = (f32x4){0.f, 0.f, 0.f, 0.f};
  char* qrow = (char*)qbuf + c * 512;
  char* krow = (char*)kbuf + c * 512;
  int c7 = c & 7;
#pragma unroll 1
  for (int sb = 0; sb < 4; ++sb) {
    int y = band * 16 + sb * 4 + yl;
    dw_row(qp, wq9, y, [&](int g, const float* o) {
      short8 s0, s1;
#pragma unroll
      for (int e = 0; e < 8; ++e) { s0[e] = (short)f2bf(o[e]); s1[e] = (short)f2bf(o[e + 8]); }
      int ch0 = yl * 8 + g * 2;
      *(short8*)(qrow + 16 * (ch0 ^ c7)) = s0;
      *(short8*)(qrow + 16 * ((ch0 + 1) ^ c7)) = s1;
    });
    dw_row(kp, wk9, y, [&](int g, const float* o) {
      short8 s0, s1;
#pragma unroll
      for (int e = 0; e < 8; ++e) { s0[e] = (short)f2bf(o[e]); s1[e] = (short)f2bf(o[e + 8]); }
      int ch0 = yl * 8 + g * 2;
      *(short8*)(krow + 16 * (ch0 ^ c7)) = s0;
      *(short8*)(krow + 16 * ((ch0 + 1) ^ c7)) = s1;
    });
    __syncthreads();
    const char* qb = (const char*)qbuf + (wv * 16 + lrow) * 512;
    int ca7 = (wv * 16 + lrow) & 7;
#pragma unroll
    for (int ks = 0; ks < 8; ++ks) {
      bf8_t aF = *(const bf8_t*)(qb + 16 * ((ks * 4 + lkg) ^ ca7));
#pragma unroll
      for (int n = 0; n < 4; ++n) {
        int cb = n * 16 + lrow;
        bf8_t bF = *(const bf8_t*)((const char*)kbuf + cb * 512 + 16 * ((ks * 4 + lkg) ^ (cb & 7)));
        acc[n] = __builtin_amdgcn_mfma_f32_16x16x32_bf16(aF, bF, acc[n], 0, 0, 0);
      }
    }
    __syncthreads();
  }
  float* Eo = E + (((size_t)band * 16 + b) * 8 + h) * 4096;
  int orow = (lane >> 4) * 4, ocol = lane & 15;
#pragma unroll
  for (int n = 0; n < 4; ++n)
#pragma unroll
    for (int i = 0; i < 4; ++i)
      Eo[(wv * 16 + orow + i) * 64 + n * 16 + ocol] = acc[n][i];
}

// ---------------- K2b: fused dw(v) -> Vt[b][n][c] bf16 ----------------
__global__ __launch_bounds__(256, 2) void k_dwV(const u16* __restrict__ Y,
    const float* __restrict__ hwd, u16* __restrict__ Vt) {
  int band = blockIdx.x, ct = blockIdx.y, b = blockIdx.z;
  __shared__ float vb[256 * 68];
  int tid = threadIdx.x;
  int c = ((tid >> 5) << 3) | (tid & 7);
  int yl = (tid >> 3) & 3;
  int cg = tid & 7;
  int cglob = ct * 64 + c;
  const u16* plane = Y + ((size_t)b * 1536 + 1024 + cglob) * 4096;
  float w9[9];
#pragma unroll
  for (int t = 0; t < 9; ++t) w9[t] = hwd[cglob * 9 + t];
#pragma unroll 1
  for (int sb = 0; sb < 4; ++sb) {
    int y = band * 16 + sb * 4 + yl;
    dw_row(plane, w9, y, [&](int g, const float* o) {
#pragma unroll
      for (int e = 0; e < 16; ++e)
        vb[((g * 16 + e) * 4 + yl) * 68 + c] = o[e];
    });
    __syncthreads();
#pragma unroll
    for (int k = 0; k < 8; ++k) {
      int np = (tid >> 3) + 32 * k;
      int x = np >> 2, yy = np & 3;
      int ng = (band * 16 + sb * 4 + yy) * 64 + x;
      f32x4 r0 = *(const f32x4*)&vb[np * 68 + cg * 8];
      f32x4 r1 = *(const f32x4*)&vb[np * 68 + cg * 8 + 4];
      short8 s;
#pragma unroll
      for (int e = 0; e < 4; ++e) { s[e] = (short)f2bf(r0[e]); s[e + 4] = (short)f2bf(r1[e]); }
      *(short8*)(Vt + ((size_t)b * 4096 + ng) * 512 + ct * 64 + cg * 8) = s;
    }
    __syncthreads();
  }
}

// ---------------- K3: fused softmax + M2 fold ----------------
// Block (h, b), 256 threads. Phase 1: threads 0..63 sum 4 E-parts, softmax row c
// -> attn in LDS. Phase 2: all threads compute M2[b][o][h*64+d].
__global__ __launch_bounds__(256) void k_sm2(const float* __restrict__ E,
    const float* __restrict__ temp, const float* __restrict__ ow, u16* __restrict__ M2) {
  int h = blockIdx.x, b = blockIdx.y;
  __shared__ float at[4096];
  int tid = threadIdx.x;
  if (tid < 64) {
    int c = tid;
    const float* pr = E + (((size_t)b * 8 + h) * 64 + c) * 64;
    float tv = temp[h];
    float e[64];
    float mx = -1e30f;
#pragma unroll
    for (int d = 0; d < 64; ++d) {
      float v = (pr[d] + pr[d + 524288] + pr[d + 1048576] + pr[d + 1572864]) * tv;
      e[d] = v;
      mx = fmaxf(mx, v);
    }
    float s = 0.f;
#pragma unroll
    for (int d = 0; d < 64; ++d) { float v = __expf(e[d] - mx); e[d] = v; s += v; }
    float inv = 1.f / s;
#pragma unroll
    for (int d = 0; d < 64; ++d) at[c * 64 + d] = e[d] * inv;
  }
  __syncthreads();
  int o4 = tid >> 2, dq = (tid & 3) * 16;
#pragma unroll 1
  for (int og = 0; og < 8; ++og) {
    int o = og * 64 + o4;
    const float* owr = ow + (size_t)o * 512 + h * 64;
    float acc[16];
#pragma unroll
    for (int e = 0; e < 16; ++e) acc[e] = 0.f;
    for (int cc = 0; cc < 64; ++cc) {
      float wv = owr[cc];
#pragma unroll
      for (int e = 0; e < 16; ++e) acc[e] += wv * at[cc * 64 + dq + e];
    }
    u16* dst = M2 + ((size_t)b * 512 + o) * 512 + h * 64 + dq;
    short8 s0, s1;
#pragma unroll
    for (int e = 0; e < 8; ++e) { s0[e] = (short)f2bf(acc[e]); s1[e] = (short)f2bf(acc[e + 8]); }
    *(short8*)dst = s0;
    *(short8*)(dst + 8) = s1;
  }
}

// ---------------- K4: out[b] = M2[b] @ v[b] + style[b]  (fp32 out; at memory floor) ----------------
__global__ __launch_bounds__(256, 2) void k_gemm_final(
    const u16* __restrict__ M2, const u16* __restrict__ Vt,
    const float* __restrict__ style, float* __restrict__ out) {
  int b = blockIdx.z;
  const u16* A = M2 + (size_t)b * (512 * 512);
  const u16* B = Vt + (size_t)b * (4096 * 512);
  const float* st = style + (size_t)b * (512 * 4096);
  float* op = out + (size_t)b * (512 * 4096);
  int M0 = blockIdx.y * 128, N0 = blockIdx.x * 128;
  int tid = threadIdx.x, wave = tid >> 6, lane = tid & 63;
  int wm = wave >> 1, wn = wave & 1;
  __shared__ __align__(16) u16 lA[2][128 * 32];
  __shared__ __align__(16) u16 lB[2][128 * 32];
  f32x4 acc[4][4];
#pragma unroll
  for (int m = 0; m < 4; ++m)
#pragma unroll
    for (int n = 0; n < 4; ++n) acc[m][n] = (f32x4){0.f, 0.f, 0.f, 0.f};
  stage_tile(A, M0, 0, &lA[0][0], wave, lane);
  stage_tile(B, N0, 0, &lB[0][0], wave, lane);
  __syncthreads();
  int lrow = lane & 15, lk = (lane >> 4) * 8;
#pragma unroll 2
  for (int kt = 0; kt < 16; ++kt) {
    int cur = kt & 1;
    if (kt < 15) {
      stage_tile(A, M0, (kt + 1) * 32, &lA[cur ^ 1][0], wave, lane);
      stage_tile(B, N0, (kt + 1) * 32, &lB[cur ^ 1][0], wave, lane);
    }
    bf8_t af[4], bff[4];
#pragma unroll
    for (int m = 0; m < 4; ++m)
      af[m] = *(const bf8_t*)&lA[cur][(wm * 64 + m * 16 + lrow) * 32 + lk];
#pragma unroll
    for (int n = 0; n < 4; ++n)
      bff[n] = *(const bf8_t*)&lB[cur][(wn * 64 + n * 16 + lrow) * 32 + lk];
#pragma unroll
    for (int m = 0; m < 4; ++m)
#pragma unroll
      for (int n = 0; n < 4; ++n)
        acc[m][n] = __builtin_amdgcn_mfma_f32_16x16x32_bf16(af[m], bff[n], acc[m][n], 0, 0, 0);
    __syncthreads();
  }
  int orow = (lane >> 4) * 4, ocol = lane & 15;
#pragma unroll
  for (int m = 0; m < 4; ++m)
#pragma unroll
    for (int n = 0; n < 4; ++n) {
      int row = M0 + wm * 64 + m * 16 + orow;
      int col = N0 + wn * 64 + n * 16 + ocol;
      float* cp = op + (size_t)row * 4096 + col;
      const float* sp = st + (size_t)row * 4096 + col;
#pragma unroll
      for (int i = 0; i < 4; ++i) cp[(size_t)i * 4096] = acc[m][n][i] + sp[(size_t)i * 4096];
    }
}

// ---------------- workspace layout (bytes) ----------------
// Wbf : [3*512][512] bf16             @ 0         (1.5 MB, rounded to 2 MB)
// Y   : [16][1536][4096] bf16         @ 2 MB      (192 MB)  PRE-dw q,k,v (never mutated)
// Xt  : [16][4096][512] bf16          @ 203423744 (64 MB)   reused as Vt after branch GEMM
// E   : [4][16][8][64][64] f32        @ 270532608 (8 MB)
// M2  : [16][512][512] bf16           @ 278921216 (8 MB)

extern "C" void kernel_launch(void* const* d_in, const int* in_sizes, int n_in,
                              void* d_out, int out_size, void* d_ws, size_t ws_size,
                              hipStream_t stream) {
  const float* style = (const float*)d_in[0];
  const float* fw1   = (const float*)d_in[1];
  const float* fwd_  = (const float*)d_in[2];
  const float* gw1   = (const float*)d_in[3];
  const float* gwd   = (const float*)d_in[4];
  const float* hw1   = (const float*)d_in[5];
  const float* hwd   = (const float*)d_in[6];
  const float* ow    = (const float*)d_in[7];
  const float* temp  = (const float*)d_in[8];
  float* out = (float*)d_out;

  char* ws = (char*)d_ws;
  u16*   Wbf = (u16*)(ws + 0);
  u16*   Y   = (u16*)(ws + (size_t)2097152);
  u16*   Xt  = (u16*)(ws + (size_t)203423744);
  u16*   Vt  = Xt;                         // Xt dead after branch GEMM; Vt born in k_dwV
  float* E   = (float*)(ws + (size_t)270532608);
  u16*   M2  = (u16*)(ws + (size_t)278921216);

  k_wconv<<<768, 256, 0, stream>>>(fw1, gw1, hw1, Wbf);
  k_xt<<<dim3(128, 16, 16), 256, 0, stream>>>(style, Xt);
  k_gemm_branch<<<dim3(32, 4, 48), 256, 0, stream>>>(Wbf, Xt, Y);
  k_dwE<<<dim3(4, 8, 16), 256, 0, stream>>>(Y, fwd_, gwd, E);
  k_dwV<<<dim3(4, 8, 16), 256, 0, stream>>>(Y, hwd, Vt);
  k_sm2<<<dim3(8, 16), 256, 0, stream>>>(E, temp, ow, M2);
  k_gemm_final<<<dim3(32, 4, 16), 256, 0, stream>>>(M2, Vt, style, out);
}

// Round 6
// 404.033 us; speedup vs baseline: 1.0300x; 1.0300x over previous
//
#include <hip/hip_runtime.h>

typedef unsigned short u16;
typedef __bf16 bf8_t __attribute__((ext_vector_type(8)));
typedef short short8 __attribute__((ext_vector_type(8)));
typedef u16 u16x4 __attribute__((ext_vector_type(4)));
typedef float f32x4 __attribute__((ext_vector_type(4)));

#define DEV __device__ __forceinline__

DEV u16 f2bf(float x) {
  unsigned u = __builtin_bit_cast(unsigned, x);
  return (u16)((u + 0x7FFFu + ((u >> 16) & 1u)) >> 16);
}
DEV float bf2f(u16 x) {
  unsigned u = (unsigned)x << 16;
  return __builtin_bit_cast(float, u);
}

DEV void gload16(const u16* g, u16* l) {
  __builtin_amdgcn_global_load_lds((__attribute__((address_space(1))) void*)(g),
                                   (__attribute__((address_space(3))) void*)(l), 16, 0, 0);
}

// ---------------- K0a: pointwise weights fp32 -> bf16, stacked [3*512][512], float4 ----------------
__global__ void k_wconv(const float* __restrict__ f, const float* __restrict__ g,
                        const float* __restrict__ h, u16* __restrict__ out) {
  int i4 = (blockIdx.x * 256 + threadIdx.x) * 4;   // 0..786428, 262144-aligned chunks
  const float* src = (i4 < 262144) ? (f + i4) : (i4 < 524288) ? (g + i4 - 262144) : (h + i4 - 524288);
  f32x4 v = *(const f32x4*)src;
  u16x4 o;
#pragma unroll
  for (int e = 0; e < 4; ++e) o[e] = f2bf(v[e]);
  *(u16x4*)(out + i4) = o;
}

// ---------------- K0b: style [b][c][n] fp32 -> Xt [b][n][c] bf16 (round-4 validated) ----------------
__global__ __launch_bounds__(256) void k_xt(const float* __restrict__ style, u16* __restrict__ Xt) {
  __shared__ float t[32][33];
  int b = blockIdx.z, c0 = blockIdx.y * 32, n0 = blockIdx.x * 32;
  int tid = threadIdx.x, lr = tid >> 5, lc = tid & 31;
  const float* src = style + ((size_t)b * 512 + c0) * 4096 + n0;
#pragma unroll
  for (int it = 0; it < 4; ++it) {
    int r = it * 8 + lr;
    t[r][lc] = src[(size_t)r * 4096 + lc];
  }
  __syncthreads();
  u16* dst = Xt + ((size_t)b * 4096 + n0) * 512 + c0;
#pragma unroll
  for (int it = 0; it < 4; ++it) {
    int n = it * 8 + lr;
    dst[(size_t)n * 512 + lc] = f2bf(t[lc][n]);
  }
}

// ---------------- 128x128 GEMM staging helper (validated round-1 structure) ----------------
DEV void stage_tile(const u16* __restrict__ src, int row0, int kb,
                    u16* lds, int wave, int lane) {
#pragma unroll
  for (int qq = 0; qq < 2; ++qq) {
    int idx = (wave * 2 + qq) * 64 + lane;   // 0..511 16B-chunk id
    int r = idx >> 2;
    int cb = (idx & 3) * 8;
    gload16(src + (size_t)(row0 + r) * 512 + (kb + cb),
            lds + (wave * 2 + qq) * 512);    // wave-uniform base; HW adds lane*16B
  }
}

// ---------------- K1: Y[b][1536][4096] = Wall[1536][512] @ Xt[b][4096][512]^T ----------------
// EXACT round-1 dispatch order (x=32 N-tiles, y=4 M-tiles, z=t*16+b), measured 144.3us (r5).
__global__ __launch_bounds__(256, 2) void k_gemm_branch(
    const u16* __restrict__ Wall, const u16* __restrict__ Xt, u16* __restrict__ Y) {
  int z = blockIdx.z;
  int t = z >> 4, b = z & 15;
  int M0 = t * 512 + blockIdx.y * 128, N0 = blockIdx.x * 128;
  const u16* A = Wall;                                  // [1536][512]
  const u16* B = Xt + (size_t)b * (4096 * 512);         // [4096][512]
  u16* C = Y + (size_t)b * (1536 * 4096);
  int tid = threadIdx.x, wave = tid >> 6, lane = tid & 63;
  int wm = wave >> 1, wn = wave & 1;
  __shared__ __align__(16) u16 lA[2][128 * 32];
  __shared__ __align__(16) u16 lB[2][128 * 32];
  f32x4 acc[4][4];
#pragma unroll
  for (int m = 0; m < 4; ++m)
#pragma unroll
    for (int n = 0; n < 4; ++n) acc[m][n] = (f32x4){0.f, 0.f, 0.f, 0.f};
  stage_tile(A, M0, 0, &lA[0][0], wave, lane);
  stage_tile(B, N0, 0, &lB[0][0], wave, lane);
  __syncthreads();
  int lrow = lane & 15, lk = (lane >> 4) * 8;
#pragma unroll 2
  for (int kt = 0; kt < 16; ++kt) {
    int cur = kt & 1;
    if (kt < 15) {
      stage_tile(A, M0, (kt + 1) * 32, &lA[cur ^ 1][0], wave, lane);
      stage_tile(B, N0, (kt + 1) * 32, &lB[cur ^ 1][0], wave, lane);
    }
    bf8_t af[4], bff[4];
#pragma unroll
    for (int m = 0; m < 4; ++m)
      af[m] = *(const bf8_t*)&lA[cur][(wm * 64 + m * 16 + lrow) * 32 + lk];
#pragma unroll
    for (int n = 0; n < 4; ++n)
      bff[n] = *(const bf8_t*)&lB[cur][(wn * 64 + n * 16 + lrow) * 32 + lk];
#pragma unroll
    for (int m = 0; m < 4; ++m)
#pragma unroll
      for (int n = 0; n < 4; ++n)
        acc[m][n] = __builtin_amdgcn_mfma_f32_16x16x32_bf16(af[m], bff[n], acc[m][n], 0, 0, 0);
    __syncthreads();
  }
  int orow = (lane >> 4) * 4, ocol = lane & 15;
#pragma unroll
  for (int m = 0; m < 4; ++m)
#pragma unroll
    for (int n = 0; n < 4; ++n) {
      int row = M0 + wm * 64 + m * 16 + orow;
      int col = N0 + wn * 64 + n * 16 + ocol;
      u16* cp = C + (size_t)row * 4096 + col;
#pragma unroll
      for (int i = 0; i < 4; ++i) cp[(size_t)i * 4096] = f2bf(acc[m][n][i]);
    }
}

// ---------------- fused depthwise row computation ----------------
template <typename F>
DEV void dw_row(const u16* plane, const float* w9, int y, F&& store) {
  short8 raw[3][8];
#pragma unroll
  for (int i = 0; i < 3; ++i) {
    int yy = y + 2 * i - 2;
    yy = yy < 0 ? -yy : (yy > 63 ? 126 - yy : yy);
    const short8* rp = (const short8*)(plane + yy * 64);
#pragma unroll
    for (int ch = 0; ch < 8; ++ch) raw[i][ch] = rp[ch];
  }
#pragma unroll
  for (int g = 0; g < 4; ++g) {
    float fr[3][20];
#pragma unroll
    for (int t = 0; t < 20; ++t) {
      int p = g * 16 - 2 + t;
      int rp2 = p < 0 ? -p : (p > 63 ? 126 - p : p);
#pragma unroll
      for (int i = 0; i < 3; ++i)
        fr[i][t] = bf2f((u16)raw[i][rp2 >> 3][rp2 & 7]);
    }
    float o[16];
#pragma unroll
    for (int e = 0; e < 16; ++e) {
      float s = 0.f;
#pragma unroll
      for (int i = 0; i < 3; ++i)
#pragma unroll
        for (int j = 0; j < 3; ++j)
          s += w9[i * 3 + j] * fr[i][e + 2 * j];
      o[e] = s;
    }
    store(g, o);
  }
}

// ---------------- K2: fused dw(q),dw(k) -> partial Gram E[band][b][h][64][64] ----------------
__global__ __launch_bounds__(256, 2) void k_dwE(const u16* __restrict__ Y,
    const float* __restrict__ fwd, const float* __restrict__ gwd, float* __restrict__ E) {
  int band = blockIdx.x, h = blockIdx.y, b = blockIdx.z;
  __shared__ __align__(16) u16 qbuf[64 * 256];
  __shared__ __align__(16) u16 kbuf[64 * 256];
  int tid = threadIdx.x;
  int c = ((tid >> 5) << 3) | (tid & 7);
  int yl = (tid >> 3) & 3;
  int wv = tid >> 6, lane = tid & 63;
  int lrow = lane & 15, lkg = lane >> 4;
  const u16* qp = Y + ((size_t)b * 1536 + h * 64 + c) * 4096;
  const u16* kp = Y + ((size_t)b * 1536 + 512 + h * 64 + c) * 4096;
  float wq9[9], wk9[9];
#pragma unroll
  for (int t = 0; t < 9; ++t) {
    wq9[t] = fwd[(h * 64 + c) * 9 + t];
    wk9[t] = gwd[(h * 64 + c) * 9 + t];
  }
  f32x4 acc[4];
#pragma unroll
  for (int n = 0; n < 4; ++n) acc[n] = (f32x4){0.f, 0.f, 0.f, 0.f};
  char* qrow = (char*)qbuf + c * 512;
  char* krow = (char*)kbuf + c * 512;
  int c7 = c & 7;
#pragma unroll 1
  for (int sb = 0; sb < 4; ++sb) {
    int y = band * 16 + sb * 4 + yl;
    dw_row(qp, wq9, y, [&](int g, const float* o) {
      short8 s0, s1;
#pragma unroll
      for (int e = 0; e < 8; ++e) { s0[e] = (short)f2bf(o[e]); s1[e] = (short)f2bf(o[e + 8]); }
      int ch0 = yl * 8 + g * 2;
      *(short8*)(qrow + 16 * (ch0 ^ c7)) = s0;
      *(short8*)(qrow + 16 * ((ch0 + 1) ^ c7)) = s1;
    });
    dw_row(kp, wk9, y, [&](int g, const float* o) {
      short8 s0, s1;
#pragma unroll
      for (int e = 0; e < 8; ++e) { s0[e] = (short)f2bf(o[e]); s1[e] = (short)f2bf(o[e + 8]); }
      int ch0 = yl * 8 + g * 2;
      *(short8*)(krow + 16 * (ch0 ^ c7)) = s0;
      *(short8*)(krow + 16 * ((ch0 + 1) ^ c7)) = s1;
    });
    __syncthreads();
    const char* qb = (const char*)qbuf + (wv * 16 + lrow) * 512;
    int ca7 = (wv * 16 + lrow) & 7;
#pragma unroll
    for (int ks = 0; ks < 8; ++ks) {
      bf8_t aF = *(const bf8_t*)(qb + 16 * ((ks * 4 + lkg) ^ ca7));
#pragma unroll
      for (int n = 0; n < 4; ++n) {
        int cb = n * 16 + lrow;
        bf8_t bF = *(const bf8_t*)((const char*)kbuf + cb * 512 + 16 * ((ks * 4 + lkg) ^ (cb & 7)));
        acc[n] = __builtin_amdgcn_mfma_f32_16x16x32_bf16(aF, bF, acc[n], 0, 0, 0);
      }
    }
    __syncthreads();
  }
  float* Eo = E + (((size_t)band * 16 + b) * 8 + h) * 4096;
  int orow = (lane >> 4) * 4, ocol = lane & 15;
#pragma unroll
  for (int n = 0; n < 4; ++n)
#pragma unroll
    for (int i = 0; i < 4; ++i)
      Eo[(wv * 16 + orow + i) * 64 + n * 16 + ocol] = acc[n][i];
}

// ---------------- K2b: fused dw(v) -> Vt[b][n][c] bf16 ----------------
__global__ __launch_bounds__(256, 2) void k_dwV(const u16* __restrict__ Y,
    const float* __restrict__ hwd, u16* __restrict__ Vt) {
  int band = blockIdx.x, ct = blockIdx.y, b = blockIdx.z;
  __shared__ float vb[256 * 68];
  int tid = threadIdx.x;
  int c = ((tid >> 5) << 3) | (tid & 7);
  int yl = (tid >> 3) & 3;
  int cg = tid & 7;
  int cglob = ct * 64 + c;
  const u16* plane = Y + ((size_t)b * 1536 + 1024 + cglob) * 4096;
  float w9[9];
#pragma unroll
  for (int t = 0; t < 9; ++t) w9[t] = hwd[cglob * 9 + t];
#pragma unroll 1
  for (int sb = 0; sb < 4; ++sb) {
    int y = band * 16 + sb * 4 + yl;
    dw_row(plane, w9, y, [&](int g, const float* o) {
#pragma unroll
      for (int e = 0; e < 16; ++e)
        vb[((g * 16 + e) * 4 + yl) * 68 + c] = o[e];
    });
    __syncthreads();
#pragma unroll
    for (int k = 0; k < 8; ++k) {
      int np = (tid >> 3) + 32 * k;
      int x = np >> 2, yy = np & 3;
      int ng = (band * 16 + sb * 4 + yy) * 64 + x;
      f32x4 r0 = *(const f32x4*)&vb[np * 68 + cg * 8];
      f32x4 r1 = *(const f32x4*)&vb[np * 68 + cg * 8 + 4];
      short8 s;
#pragma unroll
      for (int e = 0; e < 4; ++e) { s[e] = (short)f2bf(r0[e]); s[e + 4] = (short)f2bf(r1[e]); }
      *(short8*)(Vt + ((size_t)b * 4096 + ng) * 512 + ct * 64 + cg * 8) = s;
    }
    __syncthreads();
  }
}

// ---------------- K3s: softmax over d (4 partial bands summed; in place into part 0) ----------------
__global__ __launch_bounds__(64) void k_softmax(float* __restrict__ E, const float* __restrict__ temp) {
  int bh = blockIdx.x;          // b*8+h
  int b = bh >> 3, h = bh & 7;
  int c = threadIdx.x;
  float* p0 = E + (((size_t)b * 8 + h) * 64 + c) * 64;
  float tv = temp[h];
  float e[64];
  float mx = -1e30f;
#pragma unroll
  for (int d = 0; d < 64; ++d) {
    float v = (p0[d] + p0[d + 524288] + p0[d + 1048576] + p0[d + 1572864]) * tv;
    e[d] = v;
    mx = fmaxf(mx, v);
  }
  float s = 0.f;
#pragma unroll
  for (int d = 0; d < 64; ++d) { float v = __expf(e[d] - mx); e[d] = v; s += v; }
  float inv = 1.f / s;
#pragma unroll
  for (int d = 0; d < 64; ++d) p0[d] = e[d] * inv;
}

// ---------------- K3b: M2[b][o][h*64+d] = sum_cc ow[o][h*64+cc]*attn[b][h][cc][d] ----------------
__global__ __launch_bounds__(256) void k_m2(const float* __restrict__ E, const float* __restrict__ ow,
                                            u16* __restrict__ M2) {
  int og = blockIdx.x, h = blockIdx.y, b = blockIdx.z;
  __shared__ float at[4096];
  int tid = threadIdx.x;
  const float* attn = E + ((size_t)b * 8 + h) * 4096;
  for (int v = tid; v < 4096; v += 256) at[v] = attn[v];
  __syncthreads();
  int o = og * 64 + (tid >> 2), dq = (tid & 3) * 16;
  const float* owr = ow + (size_t)o * 512 + h * 64;
  float acc[16];
#pragma unroll
  for (int e = 0; e < 16; ++e) acc[e] = 0.f;
  for (int cc = 0; cc < 64; ++cc) {
    float wv = owr[cc];
#pragma unroll
    for (int e = 0; e < 16; ++e) acc[e] += wv * at[cc * 64 + dq + e];
  }
  u16* dst = M2 + ((size_t)b * 512 + o) * 512 + h * 64 + dq;
  short8 s0, s1;
#pragma unroll
  for (int e = 0; e < 8; ++e) { s0[e] = (short)f2bf(acc[e]); s1[e] = (short)f2bf(acc[e + 8]); }
  *(short8*)dst = s0;
  *(short8*)(dst + 8) = s1;
}

// ---------------- K4: out[b] = M2[b] @ v[b] + style[b]  (fp32 out; at memory floor) ----------------
__global__ __launch_bounds__(256, 2) void k_gemm_final(
    const u16* __restrict__ M2, const u16* __restrict__ Vt,
    const float* __restrict__ style, float* __restrict__ out) {
  int b = blockIdx.z;
  const u16* A = M2 + (size_t)b * (512 * 512);
  const u16* B = Vt + (size_t)b * (4096 * 512);
  const float* st = style + (size_t)b * (512 * 4096);
  float* op = out + (size_t)b * (512 * 4096);
  int M0 = blockIdx.y * 128, N0 = blockIdx.x * 128;
  int tid = threadIdx.x, wave = tid >> 6, lane = tid & 63;
  int wm = wave >> 1, wn = wave & 1;
  __shared__ __align__(16) u16 lA[2][128 * 32];
  __shared__ __align__(16) u16 lB[2][128 * 32];
  f32x4 acc[4][4];
#pragma unroll
  for (int m = 0; m < 4; ++m)
#pragma unroll
    for (int n = 0; n < 4; ++n) acc[m][n] = (f32x4){0.f, 0.f, 0.f, 0.f};
  stage_tile(A, M0, 0, &lA[0][0], wave, lane);
  stage_tile(B, N0, 0, &lB[0][0], wave, lane);
  __syncthreads();
  int lrow = lane & 15, lk = (lane >> 4) * 8;
#pragma unroll 2
  for (int kt = 0; kt < 16; ++kt) {
    int cur = kt & 1;
    if (kt < 15) {
      stage_tile(A, M0, (kt + 1) * 32, &lA[cur ^ 1][0], wave, lane);
      stage_tile(B, N0, (kt + 1) * 32, &lB[cur ^ 1][0], wave, lane);
    }
    bf8_t af[4], bff[4];
#pragma unroll
    for (int m = 0; m < 4; ++m)
      af[m] = *(const bf8_t*)&lA[cur][(wm * 64 + m * 16 + lrow) * 32 + lk];
#pragma unroll
    for (int n = 0; n < 4; ++n)
      bff[n] = *(const bf8_t*)&lB[cur][(wn * 64 + n * 16 + lrow) * 32 + lk];
#pragma unroll
    for (int m = 0; m < 4; ++m)
#pragma unroll
      for (int n = 0; n < 4; ++n)
        acc[m][n] = __builtin_amdgcn_mfma_f32_16x16x32_bf16(af[m], bff[n], acc[m][n], 0, 0, 0);
    __syncthreads();
  }
  int orow = (lane >> 4) * 4, ocol = lane & 15;
#pragma unroll
  for (int m = 0; m < 4; ++m)
#pragma unroll
    for (int n = 0; n < 4; ++n) {
      int row = M0 + wm * 64 + m * 16 + orow;
      int col = N0 + wn * 64 + n * 16 + ocol;
      float* cp = op + (size_t)row * 4096 + col;
      const float* sp = st + (size_t)row * 4096 + col;
#pragma unroll
      for (int i = 0; i < 4; ++i) cp[(size_t)i * 4096] = acc[m][n][i] + sp[(size_t)i * 4096];
    }
}

// ---------------- workspace layout (bytes) ----------------
// Wbf : [3*512][512] bf16             @ 0         (1.5 MB, rounded to 2 MB)
// Y   : [16][1536][4096] bf16         @ 2 MB      (192 MB)  PRE-dw q,k,v (never mutated)
// Xt  : [16][4096][512] bf16          @ 203423744 (64 MB)   reused as Vt after branch GEMM
// E   : [4][16][8][64][64] f32        @ 270532608 (8 MB)
// M2  : [16][512][512] bf16           @ 278921216 (8 MB)

extern "C" void kernel_launch(void* const* d_in, const int* in_sizes, int n_in,
                              void* d_out, int out_size, void* d_ws, size_t ws_size,
                              hipStream_t stream) {
  const float* style = (const float*)d_in[0];
  const float* fw1   = (const float*)d_in[1];
  const float* fwd_  = (const float*)d_in[2];
  const float* gw1   = (const float*)d_in[3];
  const float* gwd   = (const float*)d_in[4];
  const float* hw1   = (const float*)d_in[5];
  const float* hwd   = (const float*)d_in[6];
  const float* ow    = (const float*)d_in[7];
  const float* temp  = (const float*)d_in[8];
  float* out = (float*)d_out;

  char* ws = (char*)d_ws;
  u16*   Wbf = (u16*)(ws + 0);
  u16*   Y   = (u16*)(ws + (size_t)2097152);
  u16*   Xt  = (u16*)(ws + (size_t)203423744);
  u16*   Vt  = Xt;                         // Xt dead after branch GEMM; Vt born in k_dwV
  float* E   = (float*)(ws + (size_t)270532608);
  u16*   M2  = (u16*)(ws + (size_t)278921216);

  k_wconv<<<768, 256, 0, stream>>>(fw1, gw1, hw1, Wbf);
  k_xt<<<dim3(128, 16, 16), 256, 0, stream>>>(style, Xt);
  k_gemm_branch<<<dim3(32, 4, 48), 256, 0, stream>>>(Wbf, Xt, Y);
  k_dwE<<<dim3(4, 8, 16), 256, 0, stream>>>(Y, fwd_, gwd, E);
  k_dwV<<<dim3(4, 8, 16), 256, 0, stream>>>(Y, hwd, Vt);
  k_softmax<<<128, 64, 0, stream>>>(E, temp);
  k_m2<<<dim3(8, 8, 16), 256, 0, stream>>>(E, ow, M2);
  k_gemm_final<<<dim3(32, 4, 16), 256, 0, stream>>>(M2, Vt, style, out);
}